// Round 1
// baseline (1457.321 us; speedup 1.0000x reference)
//
#include <hip/hip_runtime.h>

constexpr int H = 512, W = 512, NB = 8;

// One thread computes 4 consecutive x-pixels for ALL output channels at one (b, y).
// Block: (64, 4) -> 64 x-groups (256 px) x 4 rows. Grid: (2, 128, NB or 1).
template<int CIN, int COUT, bool RELU>
__global__ __launch_bounds__(256) void conv3x3_kernel(
    const float* __restrict__ in,   // [B, CIN, H, W]
    const float* __restrict__ wt,   // [COUT, CIN, 3, 3]
    float* __restrict__ out)        // [B, COUT, H, W]
{
    const int xg = blockIdx.x * 64 + threadIdx.x;   // 128 x-groups per row
    const int x0 = xg * 4;
    const int y  = blockIdx.y * 4 + threadIdx.y;
    const int b  = blockIdx.z;

    float acc[COUT][4];
#pragma unroll
    for (int o = 0; o < COUT; ++o)
#pragma unroll
        for (int j = 0; j < 4; ++j) acc[o][j] = 0.f;

    const float* inb = in + (size_t)b * CIN * H * W;

#pragma unroll
    for (int c = 0; c < CIN; ++c) {
        // 3x6 input patch: rows y-1..y+1, cols x0-1..x0+4 (zero-padded SAME)
        float patch[3][6];
#pragma unroll
        for (int r = 0; r < 3; ++r) {
            const int iy = y - 1 + r;
            if (iy >= 0 && iy < H) {
                const float* rp = inb + ((size_t)c * H + iy) * W;
                const float4 v = *(const float4*)(rp + x0);   // x0 % 4 == 0 -> aligned
                patch[r][1] = v.x; patch[r][2] = v.y; patch[r][3] = v.z; patch[r][4] = v.w;
                patch[r][0] = (x0 > 0)     ? rp[x0 - 1] : 0.f;
                patch[r][5] = (x0 + 4 < W) ? rp[x0 + 4] : 0.f;
            } else {
#pragma unroll
                for (int k = 0; k < 6; ++k) patch[r][k] = 0.f;
            }
        }
        const float* wc = wt + c * 9;   // w[o][c][ky][kx] at (o*CIN + c)*9 + ky*3 + kx
#pragma unroll
        for (int o = 0; o < COUT; ++o) {
            const float* wo = wc + o * CIN * 9;   // wave-uniform address -> s_load
#pragma unroll
            for (int r = 0; r < 3; ++r) {
#pragma unroll
                for (int k = 0; k < 3; ++k) {
                    const float wv = wo[r * 3 + k];
#pragma unroll
                    for (int j = 0; j < 4; ++j)
                        acc[o][j] = fmaf(wv, patch[r][k + j], acc[o][j]);
                }
            }
        }
    }

#pragma unroll
    for (int o = 0; o < COUT; ++o) {
        float4 v;
        v.x = acc[o][0]; v.y = acc[o][1]; v.z = acc[o][2]; v.w = acc[o][3];
        if (RELU) {
            v.x = fmaxf(v.x, 0.f); v.y = fmaxf(v.y, 0.f);
            v.z = fmaxf(v.z, 0.f); v.w = fmaxf(v.w, 0.f);
        }
        *(float4*)(out + (((size_t)b * COUT + o) * H + y) * W + x0) = v;
    }
}

static inline void run_net(const float* x, const float* w1, const float* wmid,
                           const float* w20, float* out, float* buf0, float* buf1,
                           int nimg, hipStream_t stream) {
    // Process `nimg` images per launch chain (grid.z = nimg).
    dim3 block(64, 4, 1);
    dim3 grid(2, H / 4, nimg);
    conv3x3_kernel<1, 8, true><<<grid, block, 0, stream>>>(x, w1, buf0);
    for (int l = 0; l < 18; ++l) {
        const float* src = (l & 1) ? buf1 : buf0;
        float*       dst = (l & 1) ? buf0 : buf1;
        conv3x3_kernel<8, 8, true><<<grid, block, 0, stream>>>(src, wmid + (size_t)l * 8 * 8 * 9, dst);
    }
    // after 18 layers (last l=17 odd -> wrote buf0)
    conv3x3_kernel<8, 1, false><<<grid, block, 0, stream>>>(buf0, w20, out);
}

extern "C" void kernel_launch(void* const* d_in, const int* in_sizes, int n_in,
                              void* d_out, int out_size, void* d_ws, size_t ws_size,
                              hipStream_t stream) {
    const float* x    = (const float*)d_in[0];   // [8,1,512,512]
    const float* w1   = (const float*)d_in[1];   // [8,1,3,3]
    const float* wmid = (const float*)d_in[2];   // [18,8,8,3,3]
    const float* w20  = (const float*)d_in[3];   // [1,8,3,3]
    float* out = (float*)d_out;                  // [8,1,512,512]

    const size_t full_buf = (size_t)NB * 8 * H * W;        // elements
    if (ws_size >= 2 * full_buf * sizeof(float)) {
        float* buf0 = (float*)d_ws;
        float* buf1 = buf0 + full_buf;
        run_net(x, w1, wmid, w20, out, buf0, buf1, NB, stream);
    } else {
        // Fallback: per-image ping-pong (needs 2 * 8*512*512 floats = 16.8 MB)
        const size_t img_buf = (size_t)8 * H * W;
        float* buf0 = (float*)d_ws;
        float* buf1 = buf0 + img_buf;
        for (int b = 0; b < NB; ++b) {
            run_net(x + (size_t)b * H * W, w1, wmid, w20,
                    out + (size_t)b * H * W, buf0, buf1, 1, stream);
        }
    }
}

// Round 2
// 1081.418 us; speedup vs baseline: 1.3476x; 1.3476x over previous
//
#include <hip/hip_runtime.h>

constexpr int H = 512, W = 512, NB = 8;
constexpr int Hp = H + 2, Wp = W + 8;           // padded plane: data pixel (y,x) at (y+1, x+4)
constexpr size_t PLANE = (size_t)Hp * Wp;       // 514*520 = 267280

// Zero the border cells of `nplanes` consecutive padded planes.
// Per plane: rows 0 and Hp-1 fully (2*Wp), plus cols {0..3, Wp-4..Wp-1} of rows 1..Hp-2.
__global__ void zero_borders(float* __restrict__ buf) {
    const int plane = blockIdx.y;
    const int i = blockIdx.x * 256 + threadIdx.x;
    float* p = buf + (size_t)plane * PLANE;
    const int topbot = 2 * Wp;            // 1040
    const int sides  = (Hp - 2) * 8;      // 4096
    if (i < topbot) {
        const int r = (i < Wp) ? 0 : (Hp - 1);
        const int c = (i < Wp) ? i : (i - Wp);
        p[(size_t)r * Wp + c] = 0.f;
    } else if (i < topbot + sides) {
        const int j = i - topbot;
        const int r = 1 + (j >> 3);
        int c = j & 7;
        c = (c < 4) ? c : (Wp - 8 + c);
        p[(size_t)r * Wp + c] = 0.f;
    }
}

// conv1: 1 -> 8 channels + ReLU. Reads unpadded x, writes padded buf.
// Thread = 4 px x 8 outch. Block (64,4). Grid (2, 128, nimg).
__global__ __launch_bounds__(256) void conv1_kernel(
    const float* __restrict__ in,   // [nimg,1,H,W]
    const float* __restrict__ wt,   // [8,1,3,3]
    float* __restrict__ out)        // padded [nimg,8,Hp,Wp]
{
    const int x0 = (blockIdx.x * 64 + threadIdx.x) * 4;
    const int y  = blockIdx.y * 4 + threadIdx.y;
    const int b  = blockIdx.z;
    const float* inb = in + (size_t)b * H * W;

    float patch[3][6];
#pragma unroll
    for (int r = 0; r < 3; ++r) {
        const int iy = y - 1 + r;
        if (iy >= 0 && iy < H) {
            const float* rp = inb + (size_t)iy * W;
            const float4 v = *(const float4*)(rp + x0);
            patch[r][1] = v.x; patch[r][2] = v.y; patch[r][3] = v.z; patch[r][4] = v.w;
            patch[r][0] = (x0 > 0)     ? rp[x0 - 1] : 0.f;
            patch[r][5] = (x0 + 4 < W) ? rp[x0 + 4] : 0.f;
        } else {
#pragma unroll
            for (int k = 0; k < 6; ++k) patch[r][k] = 0.f;
        }
    }

#pragma unroll
    for (int o = 0; o < 8; ++o) {
        float a0 = 0.f, a1 = 0.f, a2 = 0.f, a3 = 0.f;
        const float* wo = wt + o * 9;
#pragma unroll
        for (int r = 0; r < 3; ++r)
#pragma unroll
            for (int k = 0; k < 3; ++k) {
                const float wv = wo[r * 3 + k];
                a0 = fmaf(wv, patch[r][k + 0], a0);
                a1 = fmaf(wv, patch[r][k + 1], a1);
                a2 = fmaf(wv, patch[r][k + 2], a2);
                a3 = fmaf(wv, patch[r][k + 3], a3);
            }
        float4 v;
        v.x = fmaxf(a0, 0.f); v.y = fmaxf(a1, 0.f);
        v.z = fmaxf(a2, 0.f); v.w = fmaxf(a3, 0.f);
        float* op = out + ((size_t)(b * 8 + o)) * PLANE + (size_t)(y + 1) * Wp + 4 + x0;
        *(float4*)op = v;
    }
}

// Mid/final conv: 8 -> COUT channels, padded input, straight-line loads.
// Thread = 8 px x COUT outch. Block (64,4): 64 threads * 8 px = 512 cols, 4 rows.
// Grid (128, nimg). Exactly 4 blocks/CU resident at nimg=8.
template<int COUT, bool RELU, bool OUT_PADDED>
__global__ __launch_bounds__(256, 4) void convmid_kernel(
    const float* __restrict__ in,   // padded [nimg,8,Hp,Wp]
    const float* __restrict__ wt,   // [COUT,8,3,3]
    float* __restrict__ out)        // padded [nimg,COUT,Hp,Wp] or unpadded [nimg,COUT,H,W]
{
    const int x0 = threadIdx.x * 8;
    const int y  = blockIdx.x * 4 + threadIdx.y;
    const int b  = blockIdx.y;

    float acc[COUT][8];
#pragma unroll
    for (int o = 0; o < COUT; ++o)
#pragma unroll
        for (int j = 0; j < 8; ++j) acc[o][j] = 0.f;

    // pointer to pixel (y-1, x0) of channel 0's padded plane
    const float* inb = in + (size_t)b * 8 * PLANE + (size_t)y * Wp + 4 + x0;

#pragma unroll
    for (int c = 0; c < 8; ++c) {
        const float* wc = wt + c * 9;
#pragma unroll
        for (int r = 0; r < 3; ++r) {
            const float* p = inb + (size_t)c * PLANE + (size_t)r * Wp;
            // window x0-1 .. x0+8 : all in-bounds thanks to padding, no branches
            const float  lm = p[-1];
            const float4 a  = *(const float4*)(p);
            const float4 bq = *(const float4*)(p + 4);
            const float  rm = p[8];
            const float win[10] = {lm, a.x, a.y, a.z, a.w, bq.x, bq.y, bq.z, bq.w, rm};
#pragma unroll
            for (int o = 0; o < COUT; ++o) {
                const float* wo = wc + o * 72 + r * 3;
#pragma unroll
                for (int k = 0; k < 3; ++k) {
                    const float wv = wo[k];
#pragma unroll
                    for (int j = 0; j < 8; ++j)
                        acc[o][j] = fmaf(wv, win[k + j], acc[o][j]);
                }
            }
        }
    }

#pragma unroll
    for (int o = 0; o < COUT; ++o) {
        float4 v0, v1;
        v0.x = acc[o][0]; v0.y = acc[o][1]; v0.z = acc[o][2]; v0.w = acc[o][3];
        v1.x = acc[o][4]; v1.y = acc[o][5]; v1.z = acc[o][6]; v1.w = acc[o][7];
        if (RELU) {
            v0.x = fmaxf(v0.x, 0.f); v0.y = fmaxf(v0.y, 0.f);
            v0.z = fmaxf(v0.z, 0.f); v0.w = fmaxf(v0.w, 0.f);
            v1.x = fmaxf(v1.x, 0.f); v1.y = fmaxf(v1.y, 0.f);
            v1.z = fmaxf(v1.z, 0.f); v1.w = fmaxf(v1.w, 0.f);
        }
        if (OUT_PADDED) {
            float* op = out + ((size_t)(b * 8 + o)) * PLANE + (size_t)(y + 1) * Wp + 4 + x0;
            *(float4*)op = v0; *(float4*)(op + 4) = v1;
        } else {
            float* op = out + (((size_t)b * COUT + o) * H + y) * W + x0;
            *(float4*)op = v0; *(float4*)(op + 4) = v1;
        }
    }
}

static inline void run_group(const float* x, const float* w1, const float* wmid,
                             const float* w20, float* out, float* buf0, float* buf1,
                             int nimg, hipStream_t stream) {
    dim3 blk(64, 4, 1);
    // buf0 and buf1 are contiguous: zero borders of both in one launch
    zero_borders<<<dim3(21, 2 * nimg * 8), 256, 0, stream>>>(buf0);
    conv1_kernel<<<dim3(2, 128, nimg), blk, 0, stream>>>(x, w1, buf0);
    for (int l = 0; l < 18; ++l) {
        const float* src = (l & 1) ? buf1 : buf0;
        float*       dst = (l & 1) ? buf0 : buf1;
        convmid_kernel<8, true, true><<<dim3(128, nimg), blk, 0, stream>>>(
            src, wmid + (size_t)l * 8 * 8 * 9, dst);
    }
    // 18 layers: last (l=17) wrote buf0
    convmid_kernel<1, false, false><<<dim3(128, nimg), blk, 0, stream>>>(buf0, w20, out);
}

extern "C" void kernel_launch(void* const* d_in, const int* in_sizes, int n_in,
                              void* d_out, int out_size, void* d_ws, size_t ws_size,
                              hipStream_t stream) {
    const float* x    = (const float*)d_in[0];   // [8,1,512,512]
    const float* w1   = (const float*)d_in[1];   // [8,1,3,3]
    const float* wmid = (const float*)d_in[2];   // [18,8,8,3,3]
    const float* w20  = (const float*)d_in[3];   // [1,8,3,3]
    float* out = (float*)d_out;                  // [8,1,512,512]

    // pick largest group size g | 2 padded ping-pong buffers fit in ws
    int g = NB;
    while (g > 1 && (size_t)2 * g * 8 * PLANE * sizeof(float) > ws_size) g >>= 1;

    float* buf0 = (float*)d_ws;
    float* buf1 = buf0 + (size_t)g * 8 * PLANE;
    for (int b0 = 0; b0 < NB; b0 += g) {
        run_group(x + (size_t)b0 * H * W, w1, wmid, w20,
                  out + (size_t)b0 * H * W, buf0, buf1, g, stream);
    }
}

// Round 4
// 892.056 us; speedup vs baseline: 1.6337x; 1.2123x over previous
//
#include <hip/hip_runtime.h>

typedef _Float16 f16;
typedef _Float16 f16x8 __attribute__((ext_vector_type(8)));
typedef float v4f __attribute__((ext_vector_type(4)));

constexpr int H = 512, W = 512, NB = 8;
constexpr int ROWS = 514;               // padded rows: y+1 for y in -1..512
constexpr int COLS = 528;               // px p at col p+8, p in -8..519
constexpr int CH = 8;
constexpr size_t ROWBYTES = (size_t)COLS * CH * 2;        // 8448
constexpr size_t PLANE_ELEMS = (size_t)ROWS * COLS * CH;  // f16 per img-plane
constexpr size_t PLANE_BYTES = PLANE_ELEMS * 2;           // 4,342,272

__device__ __forceinline__ void gload_lds16(const void* g, void* l) {
    __builtin_amdgcn_global_load_lds(
        (const __attribute__((address_space(1))) unsigned int*)g,
        (__attribute__((address_space(3))) unsigned int*)l, 16, 0, 0);
}
__device__ __forceinline__ void gload_lds4(const void* g, void* l) {
    __builtin_amdgcn_global_load_lds(
        (const __attribute__((address_space(1))) unsigned int*)g,
        (__attribute__((address_space(3))) unsigned int*)l, 4, 0, 0);
}

// ---------------- zero borders of the 4 plane-sets (hi0,lo0,hi1,lo1) ----------
__global__ void zero_borders(f16* __restrict__ base, size_t set_stride) {
    const int i = blockIdx.x * 256 + threadIdx.x;
    if (i >= 9248) return;
    const int img = blockIdx.y, set = blockIdx.z;
    int row, col;
    if (i < 1056) { row = (i < 528) ? 0 : 513; col = (i < 528) ? i : i - 528; }
    else {
        const int j = i - 1056;
        row = 1 + (j >> 4);
        const int c4 = j & 15;
        col = (c4 < 8) ? c4 : 512 + c4;   // cols 0..7 and 520..527
    }
    f16x8 z = {};
    f16* p = base + (size_t)set * set_stride + ((size_t)img * ROWS + row) * COLS * CH + (size_t)col * CH;
    *(f16x8*)p = z;
}

// ---------------- conv1: 1->8 + relu, f32 in -> split hi/lo padded NHWC -------
__global__ __launch_bounds__(256) void conv1_kernel(
    const float* __restrict__ in, const float* __restrict__ wt,  // [8][9]
    f16* __restrict__ out_hi, f16* __restrict__ out_lo)
{
    const int x0 = (blockIdx.x * 64 + threadIdx.x) * 4;
    const int y  = blockIdx.y * 4 + threadIdx.y;
    const int b  = blockIdx.z;
    const float* inb = in + (size_t)b * H * W;

    float patch[3][6];
#pragma unroll
    for (int r = 0; r < 3; ++r) {
        const int iy = y - 1 + r;
        if (iy >= 0 && iy < H) {
            const float* rp = inb + (size_t)iy * W;
            const float4 v = *(const float4*)(rp + x0);
            patch[r][1] = v.x; patch[r][2] = v.y; patch[r][3] = v.z; patch[r][4] = v.w;
            patch[r][0] = (x0 > 0)     ? rp[x0 - 1] : 0.f;
            patch[r][5] = (x0 + 4 < W) ? rp[x0 + 4] : 0.f;
        } else {
#pragma unroll
            for (int k = 0; k < 6; ++k) patch[r][k] = 0.f;
        }
    }

    float acc[8][4];
#pragma unroll
    for (int o = 0; o < 8; ++o) {
        const float* wo = wt + o * 9;
        float a0 = 0.f, a1 = 0.f, a2 = 0.f, a3 = 0.f;
#pragma unroll
        for (int r = 0; r < 3; ++r)
#pragma unroll
            for (int k = 0; k < 3; ++k) {
                const float wv = wo[r * 3 + k];
                a0 = fmaf(wv, patch[r][k + 0], a0);
                a1 = fmaf(wv, patch[r][k + 1], a1);
                a2 = fmaf(wv, patch[r][k + 2], a2);
                a3 = fmaf(wv, patch[r][k + 3], a3);
            }
        acc[o][0] = a0; acc[o][1] = a1; acc[o][2] = a2; acc[o][3] = a3;
    }

#pragma unroll
    for (int j = 0; j < 4; ++j) {
        f16x8 hv, lv;
#pragma unroll
        for (int o = 0; o < 8; ++o) {
            const float v = fmaxf(acc[o][j], 0.f);
            const f16 h = (f16)v;
            hv[o] = h;
            lv[o] = (f16)(v - (float)h);
        }
        const size_t off = (((size_t)b * ROWS + (y + 1)) * COLS + (x0 + j + 8)) * CH;
        *(f16x8*)(out_hi + off) = hv;
        *(f16x8*)(out_lo + off) = lv;
    }
}

// ---------------- MFMA conv: 8 -> COUT (padded split in; padded split or f32 out)
// Block 256 = 4 waves. Block tile: 128 px (x) by 8 output rows.
// Wave w: output rows Y=y0+2w, Y+1 via the 16-col trick; 8 x-subtiles of 16 px.
// k = tap*8+ch, taps 0..11 = (ty,tx), ty=-1..2, tx=-1..1. Cols 0-7: row Y (taps 0-8);
// cols 8-15: row Y+1 (taps 3-11 shifted). 3 MFMA passes: Ahi*Bhi + Ahi*Blo + Alo*Bhi.
template<int COUT, bool RELU, bool FINAL>
__global__ __launch_bounds__(256) void convmfma(
    const f16* __restrict__ in_hi, const f16* __restrict__ in_lo,
    const float* __restrict__ wt,          // [COUT][8][3][3]
    f16* __restrict__ out_hi, f16* __restrict__ out_lo,
    float* __restrict__ out_final)
{
    __shared__ __align__(16) f16 lds_hi[10 * 144 * CH];   // 23040 B
    __shared__ __align__(16) f16 lds_lo[10 * 144 * CH];   // 23040 B
    __shared__ __align__(16) float lds_ep[4][256];        // 4096 B

    const int wave = threadIdx.x >> 6, lane = threadIdx.x & 63;
    const int x0 = blockIdx.x * 128;
    const int y0 = blockIdx.y * 8;
    const int img = blockIdx.z;

    // ---- stage input rows y0..y0+9 (padded-row idx), px cols x0..x0+143 ----
    {
        const char* shi = (const char*)in_hi + (size_t)img * PLANE_BYTES + (size_t)x0 * 16;
        const char* slo = (const char*)in_lo + (size_t)img * PLANE_BYTES + (size_t)x0 * 16;
        char* dhi = (char*)&lds_hi[0];
        char* dlo = (char*)&lds_lo[0];
        for (int qq = wave; qq < 60; qq += 4) {
            const int p = qq / 30, rem = qq % 30, r = rem / 3, c = rem % 3;
            const char* gs = (p ? slo : shi) + (size_t)(y0 + r) * ROWBYTES;
            char* ld = (p ? dlo : dhi) + r * 2304;
            if (c < 2) gload_lds16(gs + c * 1024 + lane * 16, ld + c * 1024);
            else       gload_lds4(gs + 2048 + lane * 4, ld + 2048);
        }
    }

    // ---- build B fragments (weights hi/lo), overlap with staging loads ----
    const int n = lane & 15, q = lane >> 4, m = lane & 15;
    f16x8 bhi[3], blo[3];
#pragma unroll
    for (int g = 0; g < 3; ++g) {
        const int t = g * 4 + q;
#pragma unroll
        for (int j = 0; j < 8; ++j) {
            float wv = 0.f;
            if (n < 8) {
                if (t <= 8 && n < COUT) wv = wt[(n * 8 + j) * 9 + t];
            } else {
                const int o = n - 8;
                if (t >= 3 && o < COUT) wv = wt[(o * 8 + j) * 9 + (t - 3)];
            }
            const f16 h = (f16)wv;
            bhi[g][j] = h;
            blo[g][j] = (f16)(wv - (float)h);
        }
    }

    // per-lane A addressing (px units within staged tile)
    int abase[3];
#pragma unroll
    for (int g = 0; g < 3; ++g) {
        const int t = g * 4 + q;
        const int ty = t / 3 - 1, tx = t % 3 - 1;
        abase[g] = (2 * wave + ty + 1) * 144 + (m + tx + 8);
    }

    __syncthreads();

    const int Y = y0 + 2 * wave;
    float* ep = &lds_ep[wave][0];

#pragma unroll 2
    for (int s = 0; s < 8; ++s) {
        v4f acc = {0.f, 0.f, 0.f, 0.f}, acc2 = {0.f, 0.f, 0.f, 0.f};
#pragma unroll
        for (int g = 0; g < 3; ++g) {
            const int idx = (abase[g] + 16 * s) * CH;
            const f16x8 ah = *(const f16x8*)&lds_hi[idx];
            const f16x8 al = *(const f16x8*)&lds_lo[idx];
            acc  = __builtin_amdgcn_mfma_f32_16x16x32_f16(ah, bhi[g], acc,  0, 0, 0);
            acc2 = __builtin_amdgcn_mfma_f32_16x16x32_f16(ah, blo[g], acc2, 0, 0, 0);
            acc2 = __builtin_amdgcn_mfma_f32_16x16x32_f16(al, bhi[g], acc2, 0, 0, 0);
        }

        // epilogue: bounce through per-wave LDS to get coalesced 16B stores
#pragma unroll
        for (int r4 = 0; r4 < 4; ++r4)
            ep[(q * 4 + r4) * 16 + n] = acc[r4] + acc2[r4];
        asm volatile("s_waitcnt lgkmcnt(0)" ::: "memory");

        const int P = lane & 31;
        const int pm = P & 15, half = P >> 4;
        const float4 u0 = *(const float4*)&ep[pm * 16 + half * 8];
        const float4 u1 = *(const float4*)&ep[pm * 16 + half * 8 + 4];
        float v[8] = {u0.x, u0.y, u0.z, u0.w, u1.x, u1.y, u1.z, u1.w};
        if (RELU) {
#pragma unroll
            for (int c = 0; c < 8; ++c) v[c] = fmaxf(v[c], 0.f);
        }
        if constexpr (!FINAL) {
            f16x8 hv, lv;
#pragma unroll
            for (int c = 0; c < 8; ++c) {
                const f16 h = (f16)v[c];
                hv[c] = h;
                lv[c] = (f16)(v[c] - (float)h);
            }
            const int gy = Y + half + 1;            // padded row
            const int gx = x0 + 16 * s + pm + 8;    // padded col
            const size_t off = ((size_t)img * ROWS + gy) * COLS * CH + (size_t)gx * CH;
            f16* dst = (lane < 32) ? (out_hi + off) : (out_lo + off);
            *(f16x8*)dst = (lane < 32) ? hv : lv;
        } else {
            if (lane < 32) {
                const int gy = Y + half, gx = x0 + 16 * s + pm;
                out_final[((size_t)img * H + gy) * W + gx] = v[0];
            }
        }
        asm volatile("" ::: "memory");
    }
}

extern "C" void kernel_launch(void* const* d_in, const int* in_sizes, int n_in,
                              void* d_out, int out_size, void* d_ws, size_t ws_size,
                              hipStream_t stream) {
    const float* x    = (const float*)d_in[0];   // [8,1,512,512]
    const float* w1   = (const float*)d_in[1];   // [8,1,3,3]
    const float* wmid = (const float*)d_in[2];   // [18,8,8,3,3]
    const float* w20  = (const float*)d_in[3];   // [1,8,3,3]
    float* out = (float*)d_out;                  // [8,1,512,512]

    // group size g: need 4 plane-sets of g images each
    int g = NB;
    while (g > 1 && 4 * (size_t)g * PLANE_BYTES > ws_size) g >>= 1;

    f16* hi0 = (f16*)d_ws;
    f16* lo0 = hi0 + (size_t)g * PLANE_ELEMS;
    f16* hi1 = lo0 + (size_t)g * PLANE_ELEMS;
    f16* lo1 = hi1 + (size_t)g * PLANE_ELEMS;

    // borders are never rewritten by interior-only epilogues -> zero once
    zero_borders<<<dim3(37, g, 4), 256, 0, stream>>>(hi0, (size_t)g * PLANE_ELEMS);

    for (int b0 = 0; b0 < NB; b0 += g) {
        conv1_kernel<<<dim3(2, 128, g), dim3(64, 4), 0, stream>>>(
            x + (size_t)b0 * H * W, w1, hi0, lo0);
        for (int l = 0; l < 18; ++l) {
            const f16* shl = (l & 1) ? hi1 : hi0;
            const f16* sll = (l & 1) ? lo1 : lo0;
            f16* dhl = (l & 1) ? hi0 : hi1;
            f16* dll = (l & 1) ? lo0 : lo1;
            convmfma<8, true, false><<<dim3(4, 64, g), 256, 0, stream>>>(
                shl, sll, wmid + (size_t)l * 576, dhl, dll, nullptr);
        }
        // 18 mids: last (l=17) wrote hi0/lo0
        convmfma<1, false, true><<<dim3(4, 64, g), 256, 0, stream>>>(
            hi0, lo0, w20, nullptr, nullptr, out + (size_t)b0 * H * W);
    }
}

// Round 5
// 570.238 us; speedup vs baseline: 2.5556x; 1.5644x over previous
//
#include <hip/hip_runtime.h>

typedef _Float16 f16;
typedef _Float16 f16x8 __attribute__((ext_vector_type(8)));
typedef _Float16 f16x4 __attribute__((ext_vector_type(4)));
typedef float v4f __attribute__((ext_vector_type(4)));

constexpr int H = 512, W = 512, NB = 8;
constexpr int ROWS = 514;               // padded rows: y+1 for y in -1..512
constexpr int COLS = 528;               // px p at col p+8, p in -8..519
constexpr int CH = 8;
constexpr size_t ROWBYTES = (size_t)COLS * CH * 2;        // 8448
constexpr size_t PLANE_ELEMS = (size_t)ROWS * COLS * CH;  // f16 per img-plane
constexpr size_t PLANE_BYTES = PLANE_ELEMS * 2;           // 4,342,272

// LDS tile: 10 rows x 145 px x 8 f16; row stride padded +1 px to break the
// 2304B==0 mod 128 bank alignment that caused 1.57M conflicts in round 4.
constexpr int RSP = 145;
constexpr int LDS_ROWB = RSP * 16;      // 2320 B

__device__ __forceinline__ void gload_lds16(const void* g, void* l) {
    __builtin_amdgcn_global_load_lds(
        (const __attribute__((address_space(1))) unsigned int*)g,
        (__attribute__((address_space(3))) unsigned int*)l, 16, 0, 0);
}
__device__ __forceinline__ void gload_lds4(const void* g, void* l) {
    __builtin_amdgcn_global_load_lds(
        (const __attribute__((address_space(1))) unsigned int*)g,
        (__attribute__((address_space(3))) unsigned int*)l, 4, 0, 0);
}

// ---------------- zero borders of the 2 plane-sets (act0, act1) ---------------
__global__ void zero_borders(f16* __restrict__ base, size_t set_stride) {
    const int i = blockIdx.x * 256 + threadIdx.x;
    if (i >= 9248) return;
    const int img = blockIdx.y, set = blockIdx.z;
    int row, col;
    if (i < 1056) { row = (i < 528) ? 0 : 513; col = (i < 528) ? i : i - 528; }
    else {
        const int j = i - 1056;
        row = 1 + (j >> 4);
        const int c4 = j & 15;
        col = (c4 < 8) ? c4 : 512 + c4;   // cols 0..7 and 520..527
    }
    f16x8 z = {};
    f16* p = base + (size_t)set * set_stride + ((size_t)img * ROWS + row) * COLS * CH + (size_t)col * CH;
    *(f16x8*)p = z;
}

// ---------------- conv1: 1->8 + relu, f32 in -> f16 padded NHWC ---------------
__global__ __launch_bounds__(256) void conv1_kernel(
    const float* __restrict__ in, const float* __restrict__ wt,  // [8][9]
    f16* __restrict__ out)
{
    const int x0 = (blockIdx.x * 64 + threadIdx.x) * 4;
    const int y  = blockIdx.y * 4 + threadIdx.y;
    const int b  = blockIdx.z;
    const float* inb = in + (size_t)b * H * W;

    float patch[3][6];
#pragma unroll
    for (int r = 0; r < 3; ++r) {
        const int iy = y - 1 + r;
        if (iy >= 0 && iy < H) {
            const float* rp = inb + (size_t)iy * W;
            const float4 v = *(const float4*)(rp + x0);
            patch[r][1] = v.x; patch[r][2] = v.y; patch[r][3] = v.z; patch[r][4] = v.w;
            patch[r][0] = (x0 > 0)     ? rp[x0 - 1] : 0.f;
            patch[r][5] = (x0 + 4 < W) ? rp[x0 + 4] : 0.f;
        } else {
#pragma unroll
            for (int k = 0; k < 6; ++k) patch[r][k] = 0.f;
        }
    }

    float acc[8][4];
#pragma unroll
    for (int o = 0; o < 8; ++o) {
        const float* wo = wt + o * 9;
        float a0 = 0.f, a1 = 0.f, a2 = 0.f, a3 = 0.f;
#pragma unroll
        for (int r = 0; r < 3; ++r)
#pragma unroll
            for (int k = 0; k < 3; ++k) {
                const float wv = wo[r * 3 + k];
                a0 = fmaf(wv, patch[r][k + 0], a0);
                a1 = fmaf(wv, patch[r][k + 1], a1);
                a2 = fmaf(wv, patch[r][k + 2], a2);
                a3 = fmaf(wv, patch[r][k + 3], a3);
            }
        acc[o][0] = a0; acc[o][1] = a1; acc[o][2] = a2; acc[o][3] = a3;
    }

#pragma unroll
    for (int j = 0; j < 4; ++j) {
        f16x8 hv;
#pragma unroll
        for (int o = 0; o < 8; ++o)
            hv[o] = (f16)fmaxf(acc[o][j], 0.f);
        const size_t off = (((size_t)b * ROWS + (y + 1)) * COLS + (x0 + j + 8)) * CH;
        *(f16x8*)(out + off) = hv;
    }
}

// ---------------- MFMA conv: 8 -> COUT, f16 act, split-weight 2-pass ----------
// Block 256 = 4 waves; tile 128 px x 8 output rows. Wave w: rows Y=y0+2w, Y+1
// via 16-col trick (cols 0-7: row Y taps 0-8; cols 8-15: row Y+1 taps 3-11).
// Phase A: all 8 sub-tiles' MFMAs (24 ds_read_b128 + 48 MFMA) into 32 VGPRs.
// Phase B: per-s LDS bounce (stride-20 ep) -> coalesced f16x4 global stores.
template<int COUT, bool RELU, bool FINAL>
__global__ __launch_bounds__(256) void convmfma(
    const f16* __restrict__ in,            // padded [g,ROWS,COLS,CH] f16
    const float* __restrict__ wt,          // [COUT][8][3][3]
    f16* __restrict__ outp,                // padded f16 (mid)
    float* __restrict__ out_final)         // unpadded f32 (final)
{
    __shared__ __align__(16) f16 lds[10 * RSP * CH];      // 23200 B
    __shared__ __align__(16) float lds_ep[4][16 * 20];    // 5120 B

    const int wave = threadIdx.x >> 6, lane = threadIdx.x & 63;
    const int img = blockIdx.x;            // grid.x = img -> XCD affinity
    const int x0 = blockIdx.y * 128;
    const int y0 = blockIdx.z * 8;

    // ---- stage rows y0..y0+9, px cols x0..x0+143 into padded-stride LDS ----
    {
        const char* src = (const char*)in + (size_t)img * PLANE_BYTES + (size_t)x0 * 16;
        char* dst = (char*)&lds[0];
        for (int qq = wave; qq < 30; qq += 4) {
            const int r = qq / 3, c = qq % 3;
            const char* gs = src + (size_t)(y0 + r) * ROWBYTES;
            char* ld = dst + r * LDS_ROWB;
            if (c < 2) gload_lds16(gs + c * 1024 + lane * 16, ld + c * 1024);
            else       gload_lds4(gs + 2048 + lane * 4, ld + 2048);
        }
    }

    // ---- B fragments: weights split hi/lo (2-pass) ----
    const int n = lane & 15, q = lane >> 4, m = lane & 15;
    f16x8 bhi[3], blo[3];
#pragma unroll
    for (int g = 0; g < 3; ++g) {
        const int t = g * 4 + q;
#pragma unroll
        for (int j = 0; j < 8; ++j) {
            float wv = 0.f;
            if (n < 8) {
                if (t <= 8 && n < COUT) wv = wt[(n * 8 + j) * 9 + t];
            } else {
                const int o = n - 8;
                if (t >= 3 && o < COUT) wv = wt[(o * 8 + j) * 9 + (t - 3)];
            }
            const f16 h = (f16)wv;
            bhi[g][j] = h;
            blo[g][j] = (f16)(wv - (float)h);
        }
    }

    int abase[3];
#pragma unroll
    for (int g = 0; g < 3; ++g) {
        const int t = g * 4 + q;
        const int ty = t / 3 - 1, tx = t % 3 - 1;
        abase[g] = (2 * wave + ty + 1) * RSP + (m + tx + 8);
    }

    __syncthreads();

    // ---- Phase A: all MFMAs ----
    v4f res[8];
#pragma unroll
    for (int s = 0; s < 8; ++s) {
        v4f acc = {0.f, 0.f, 0.f, 0.f}, acc2 = {0.f, 0.f, 0.f, 0.f};
#pragma unroll
        for (int g = 0; g < 3; ++g) {
            const f16x8 ah = *(const f16x8*)&lds[(abase[g] + 16 * s) * CH];
            acc  = __builtin_amdgcn_mfma_f32_16x16x32_f16(ah, bhi[g], acc,  0, 0, 0);
            acc2 = __builtin_amdgcn_mfma_f32_16x16x32_f16(ah, blo[g], acc2, 0, 0, 0);
        }
        res[s] = acc + acc2;
    }

    // ---- Phase B: epilogue bounce (per-wave ep, stride 20 to dodge banks) ----
    const int Y = y0 + 2 * wave;
    float* ep = &lds_ep[wave][0];
    const int px = lane & 15, rowhalf = (lane >> 4) & 1, chhalf = (lane >> 5) & 1;

#pragma unroll
    for (int s = 0; s < 8; ++s) {
#pragma unroll
        for (int r4 = 0; r4 < 4; ++r4)
            ep[(q * 4 + r4) * 20 + n] = res[s][r4];
        asm volatile("s_waitcnt lgkmcnt(0)" ::: "memory");

        if constexpr (!FINAL) {
            const v4f u = *(const v4f*)&ep[px * 20 + rowhalf * 8 + chhalf * 4];
            f16x4 hv;
#pragma unroll
            for (int c = 0; c < 4; ++c) {
                float v = u[c];
                if (RELU) v = fmaxf(v, 0.f);
                hv[c] = (f16)v;
            }
            const int gy = Y + rowhalf + 1;           // padded row
            const int gx = x0 + 16 * s + px + 8;      // padded col
            *(f16x4*)(outp + ((size_t)img * ROWS + gy) * COLS * CH + (size_t)gx * CH + chhalf * 4) = hv;
        } else {
            if (lane < 32) {
                const float v = ep[px * 20 + rowhalf * 8];
                const int gy = Y + rowhalf, gx = x0 + 16 * s + px;
                out_final[((size_t)img * H + gy) * W + gx] = v;
            }
        }
        asm volatile("" ::: "memory");
    }
}

extern "C" void kernel_launch(void* const* d_in, const int* in_sizes, int n_in,
                              void* d_out, int out_size, void* d_ws, size_t ws_size,
                              hipStream_t stream) {
    const float* x    = (const float*)d_in[0];   // [8,1,512,512]
    const float* w1   = (const float*)d_in[1];   // [8,1,3,3]
    const float* wmid = (const float*)d_in[2];   // [18,8,8,3,3]
    const float* w20  = (const float*)d_in[3];   // [1,8,3,3]
    float* out = (float*)d_out;                  // [8,1,512,512]

    // group size g: need 2 plane-sets of g images each
    int g = NB;
    while (g > 1 && 2 * (size_t)g * PLANE_BYTES > ws_size) g >>= 1;

    f16* act0 = (f16*)d_ws;
    f16* act1 = act0 + (size_t)g * PLANE_ELEMS;

    // borders never rewritten by interior-only epilogues -> zero once
    zero_borders<<<dim3(37, g, 2), 256, 0, stream>>>(act0, (size_t)g * PLANE_ELEMS);

    for (int b0 = 0; b0 < NB; b0 += g) {
        conv1_kernel<<<dim3(2, 128, g), dim3(64, 4), 0, stream>>>(
            x + (size_t)b0 * H * W, w1, act0);
        for (int l = 0; l < 18; ++l) {
            const f16* s0 = (l & 1) ? act1 : act0;
            f16*       d0 = (l & 1) ? act0 : act1;
            convmfma<8, true, false><<<dim3(g, 4, 64), 256, 0, stream>>>(
                s0, wmid + (size_t)l * 576, d0, nullptr);
        }
        // 18 mids: last (l=17) wrote act0
        convmfma<1, false, true><<<dim3(g, 4, 64), 256, 0, stream>>>(
            act0, w20, nullptr, out + (size_t)b0 * H * W);
    }
}

// Round 6
// 536.488 us; speedup vs baseline: 2.7164x; 1.0629x over previous
//
#include <hip/hip_runtime.h>

typedef _Float16 f16;
typedef _Float16 f16x8 __attribute__((ext_vector_type(8)));
typedef _Float16 f16x4 __attribute__((ext_vector_type(4)));
typedef float v4f __attribute__((ext_vector_type(4)));

constexpr int H = 512, W = 512, NB = 8;
constexpr int ROWS = 514;               // padded rows: y+1 for y in -1..512
constexpr int COLS = 528;               // px p at col p+8, p in -8..519
constexpr int CH = 8;
constexpr size_t ROWBYTES = (size_t)COLS * CH * 2;        // 8448
constexpr size_t PLANE_ELEMS = (size_t)ROWS * COLS * CH;  // f16 per img-plane
constexpr size_t PLANE_BYTES = PLANE_ELEMS * 2;           // 4,342,272

// LDS tile: 10 rows x 145 px x 8 f16; +1 px row pad keeps quad rows offset by
// 4 banks -> conflict-free ds_read_b128 (round-5 fix, verified by counter drop).
constexpr int RSP = 145;
constexpr int LDS_ROWB = RSP * 16;      // 2320 B

__device__ __forceinline__ void gload_lds16(const void* g, void* l) {
    __builtin_amdgcn_global_load_lds(
        (const __attribute__((address_space(1))) unsigned int*)g,
        (__attribute__((address_space(3))) unsigned int*)l, 16, 0, 0);
}
__device__ __forceinline__ void gload_lds4(const void* g, void* l) {
    __builtin_amdgcn_global_load_lds(
        (const __attribute__((address_space(1))) unsigned int*)g,
        (__attribute__((address_space(3))) unsigned int*)l, 4, 0, 0);
}

// ---------------- zero borders of the 2 plane-sets (act0, act1) ---------------
__global__ void zero_borders(f16* __restrict__ base, size_t set_stride) {
    const int i = blockIdx.x * 256 + threadIdx.x;
    if (i >= 9248) return;
    const int img = blockIdx.y, set = blockIdx.z;
    int row, col;
    if (i < 1056) { row = (i < 528) ? 0 : 513; col = (i < 528) ? i : i - 528; }
    else {
        const int j = i - 1056;
        row = 1 + (j >> 4);
        const int c4 = j & 15;
        col = (c4 < 8) ? c4 : 512 + c4;   // cols 0..7 and 520..527
    }
    f16x8 z = {};
    f16* p = base + (size_t)set * set_stride + ((size_t)img * ROWS + row) * COLS * CH + (size_t)col * CH;
    *(f16x8*)p = z;
}

// ---------------- conv1: 1->8 + relu, f32 in -> f16 padded NHWC ---------------
__global__ __launch_bounds__(256) void conv1_kernel(
    const float* __restrict__ in, const float* __restrict__ wt,  // [8][9]
    f16* __restrict__ out)
{
    const int x0 = (blockIdx.x * 64 + threadIdx.x) * 4;
    const int y  = blockIdx.y * 4 + threadIdx.y;
    const int b  = blockIdx.z;
    const float* inb = in + (size_t)b * H * W;

    float patch[3][6];
#pragma unroll
    for (int r = 0; r < 3; ++r) {
        const int iy = y - 1 + r;
        if (iy >= 0 && iy < H) {
            const float* rp = inb + (size_t)iy * W;
            const float4 v = *(const float4*)(rp + x0);
            patch[r][1] = v.x; patch[r][2] = v.y; patch[r][3] = v.z; patch[r][4] = v.w;
            patch[r][0] = (x0 > 0)     ? rp[x0 - 1] : 0.f;
            patch[r][5] = (x0 + 4 < W) ? rp[x0 + 4] : 0.f;
        } else {
#pragma unroll
            for (int k = 0; k < 6; ++k) patch[r][k] = 0.f;
        }
    }

    float acc[8][4];
#pragma unroll
    for (int o = 0; o < 8; ++o) {
        const float* wo = wt + o * 9;
        float a0 = 0.f, a1 = 0.f, a2 = 0.f, a3 = 0.f;
#pragma unroll
        for (int r = 0; r < 3; ++r)
#pragma unroll
            for (int k = 0; k < 3; ++k) {
                const float wv = wo[r * 3 + k];
                a0 = fmaf(wv, patch[r][k + 0], a0);
                a1 = fmaf(wv, patch[r][k + 1], a1);
                a2 = fmaf(wv, patch[r][k + 2], a2);
                a3 = fmaf(wv, patch[r][k + 3], a3);
            }
        acc[o][0] = a0; acc[o][1] = a1; acc[o][2] = a2; acc[o][3] = a3;
    }

#pragma unroll
    for (int j = 0; j < 4; ++j) {
        f16x8 hv;
#pragma unroll
        for (int o = 0; o < 8; ++o)
            hv[o] = (f16)fmaxf(acc[o][j], 0.f);
        const size_t off = (((size_t)b * ROWS + (y + 1)) * COLS + (x0 + j + 8)) * CH;
        *(f16x8*)(out + off) = hv;
    }
}

// ---------------- MFMA conv: 8 -> COUT, f16 act, split-weight 2-pass ----------
// Block 256 = 4 waves; tile 128 px x 8 output rows; wave w: rows Y=y0+2w, Y+1.
// OPERAND-SWAPPED: D = W * X, so M = 16 weight-combos (outch x {rowY,rowY+1}),
// N = 16 px. A- and B-fragment lane maps are symmetric (idx=lane&15, k=q*8+j),
// so fragments are unchanged from the X*W version; only the arg order flips.
// C layout: lane(q,n) holds m = q*4+r (r=reg), col n=px -> 4 consecutive ch at
// one pixel = 8B-contiguous f16x4 direct store. No LDS epilogue, no drains.
template<int COUT, bool RELU, bool FINAL>
__global__ __launch_bounds__(256) void convmfma(
    const f16* __restrict__ in,            // padded [g,ROWS,COLS,CH] f16
    const float* __restrict__ wt,          // [COUT][8][3][3]
    f16* __restrict__ outp,                // padded f16 (mid)
    float* __restrict__ out_final)         // unpadded f32 (final)
{
    __shared__ __align__(16) f16 lds[10 * RSP * CH];      // 23200 B

    const int wave = threadIdx.x >> 6, lane = threadIdx.x & 63;
    const int img = blockIdx.x;            // grid.x = img -> XCD affinity
    const int x0 = blockIdx.y * 128;
    const int y0 = blockIdx.z * 8;

    // ---- stage rows y0..y0+9, px cols x0..x0+143 into padded-stride LDS ----
    {
        const char* src = (const char*)in + (size_t)img * PLANE_BYTES + (size_t)x0 * 16;
        char* dst = (char*)&lds[0];
        for (int qq = wave; qq < 30; qq += 4) {
            const int r = qq / 3, c = qq % 3;
            const char* gs = src + (size_t)(y0 + r) * ROWBYTES;
            char* ld = dst + r * LDS_ROWB;
            if (c < 2) gload_lds16(gs + c * 1024 + lane * 16, ld + c * 1024);
            else       gload_lds4(gs + 2048 + lane * 4, ld + 2048);
        }
    }

    // ---- weight fragments (hi/lo split, 2-pass). m<8: row Y taps 0-8 at
    // t=g*4+q; m>=8: row Y+1, taps shifted by -3. Same data as X*W version. ----
    const int n = lane & 15, q = lane >> 4, m = lane & 15;
    f16x8 bhi[3], blo[3];
#pragma unroll
    for (int g = 0; g < 3; ++g) {
        const int t = g * 4 + q;
#pragma unroll
        for (int j = 0; j < 8; ++j) {
            float wv = 0.f;
            if (n < 8) {
                if (t <= 8 && n < COUT) wv = wt[(n * 8 + j) * 9 + t];
            } else {
                const int o = n - 8;
                if (t >= 3 && o < COUT) wv = wt[(o * 8 + j) * 9 + (t - 3)];
            }
            const f16 h = (f16)wv;
            bhi[g][j] = h;
            blo[g][j] = (f16)(wv - (float)h);
        }
    }

    int abase[3];
#pragma unroll
    for (int g = 0; g < 3; ++g) {
        const int t = g * 4 + q;
        const int ty = t / 3 - 1, tx = t % 3 - 1;
        abase[g] = (2 * wave + ty + 1) * RSP + (m + tx + 8);
    }

    __syncthreads();

    const int Y = y0 + 2 * wave;
    const int rowoff = q >> 1;             // 0: row Y, 1: row Y+1
    const int choff = (q & 1) * 4;         // ch 0-3 or 4-7

#pragma unroll
    for (int s = 0; s < 8; ++s) {
        v4f acc = {0.f, 0.f, 0.f, 0.f}, acc2 = {0.f, 0.f, 0.f, 0.f};
#pragma unroll
        for (int g = 0; g < 3; ++g) {
            const f16x8 xv = *(const f16x8*)&lds[(abase[g] + 16 * s) * CH];
            // weights as A, pixels as B -> D[m=weight-combo][n=px]
            acc  = __builtin_amdgcn_mfma_f32_16x16x32_f16(bhi[g], xv, acc,  0, 0, 0);
            acc2 = __builtin_amdgcn_mfma_f32_16x16x32_f16(blo[g], xv, acc2, 0, 0, 0);
        }
        const v4f res = acc + acc2;

        if constexpr (!FINAL) {
            f16x4 hv;
#pragma unroll
            for (int c = 0; c < 4; ++c) {
                float v = res[c];
                if (RELU) v = fmaxf(v, 0.f);
                hv[c] = (f16)v;
            }
            const int gy = Y + rowoff + 1;            // padded row
            const int gx = x0 + 16 * s + n + 8;       // padded col
            *(f16x4*)(outp + ((size_t)img * ROWS + gy) * COLS * CH + (size_t)gx * CH + choff) = hv;
        } else {
            // valid outputs: m=0 (q=0,r=0) -> row Y; m=8 (q=2,r=0) -> row Y+1
            if ((q & 1) == 0) {
                const int gy = Y + rowoff, gx = x0 + 16 * s + n;
                out_final[((size_t)img * H + gy) * W + gx] = res[0];
            }
        }
    }
}

extern "C" void kernel_launch(void* const* d_in, const int* in_sizes, int n_in,
                              void* d_out, int out_size, void* d_ws, size_t ws_size,
                              hipStream_t stream) {
    const float* x    = (const float*)d_in[0];   // [8,1,512,512]
    const float* w1   = (const float*)d_in[1];   // [8,1,3,3]
    const float* wmid = (const float*)d_in[2];   // [18,8,8,3,3]
    const float* w20  = (const float*)d_in[3];   // [1,8,3,3]
    float* out = (float*)d_out;                  // [8,1,512,512]

    // group size g: need 2 plane-sets of g images each
    int g = NB;
    while (g > 1 && 2 * (size_t)g * PLANE_BYTES > ws_size) g >>= 1;

    f16* act0 = (f16*)d_ws;
    f16* act1 = act0 + (size_t)g * PLANE_ELEMS;

    // borders never rewritten by interior-only epilogues -> zero once
    zero_borders<<<dim3(37, g, 2), 256, 0, stream>>>(act0, (size_t)g * PLANE_ELEMS);

    for (int b0 = 0; b0 < NB; b0 += g) {
        conv1_kernel<<<dim3(2, 128, g), dim3(64, 4), 0, stream>>>(
            x + (size_t)b0 * H * W, w1, act0);
        for (int l = 0; l < 18; ++l) {
            const f16* s0 = (l & 1) ? act1 : act0;
            f16*       d0 = (l & 1) ? act0 : act1;
            convmfma<8, true, false><<<dim3(g, 4, 64), 256, 0, stream>>>(
                s0, wmid + (size_t)l * 576, d0, nullptr);
        }
        // 18 mids: last (l=17) wrote act0
        convmfma<1, false, true><<<dim3(g, 4, 64), 256, 0, stream>>>(
            act0, w20, nullptr, out + (size_t)b0 * H * W);
    }
}

// Round 7
// 343.034 us; speedup vs baseline: 4.2483x; 1.5640x over previous
//
#include <hip/hip_runtime.h>

typedef _Float16 f16;
typedef _Float16 f16x8 __attribute__((ext_vector_type(8)));
typedef _Float16 f16x4 __attribute__((ext_vector_type(4)));
typedef float v4f __attribute__((ext_vector_type(4)));

constexpr int H = 512, W = 512, NB = 8;
constexpr int ROWS = 514;               // padded rows: y+1 for y in -1..512
constexpr int COLS = 528;               // px p at col p+8, p in -8..519
constexpr int CH = 8;
constexpr size_t ROWBYTES = (size_t)COLS * CH * 2;        // 8448
constexpr size_t PLANE_ELEMS = (size_t)ROWS * COLS * CH;  // f16 per img-plane
constexpr size_t PLANE_BYTES = PLANE_ELEMS * 2;           // 4,342,272

// LDS tile: 10 rows x 145 px x 8 f16; +1 px row pad -> conflict-free (r5 fix).
constexpr int RSP = 145;
constexpr int LDS_ROWB = RSP * 16;      // 2320 B
constexpr int WTAB_L = 3072;            // f16 per layer: 3 g x {hi,lo} x 64 lanes x 8

__device__ __forceinline__ void gload_lds16(const void* g, void* l) {
    __builtin_amdgcn_global_load_lds(
        (const __attribute__((address_space(1))) unsigned int*)g,
        (__attribute__((address_space(3))) unsigned int*)l, 16, 0, 0);
}
__device__ __forceinline__ void gload_lds4(const void* g, void* l) {
    __builtin_amdgcn_global_load_lds(
        (const __attribute__((address_space(1))) unsigned int*)g,
        (__attribute__((address_space(3))) unsigned int*)l, 4, 0, 0);
}

// ---------------- zero borders of the 2 plane-sets (act0, act1) ---------------
__global__ void zero_borders(f16* __restrict__ base, size_t set_stride) {
    const int i = blockIdx.x * 256 + threadIdx.x;
    if (i >= 9248) return;
    const int img = blockIdx.y, set = blockIdx.z;
    int row, col;
    if (i < 1056) { row = (i < 528) ? 0 : 513; col = (i < 528) ? i : i - 528; }
    else {
        const int j = i - 1056;
        row = 1 + (j >> 4);
        const int c4 = j & 15;
        col = (c4 < 8) ? c4 : 512 + c4;   // cols 0..7 and 520..527
    }
    f16x8 z = {};
    f16* p = base + (size_t)set * set_stride + ((size_t)img * ROWS + row) * COLS * CH + (size_t)col * CH;
    *(f16x8*)p = z;
}

// ---------------- precompute per-lane weight fragments (19 layers) ------------
// Layout: wtab[l*3072 + (g*2+h)*512 + lane*8], h=0 hi, h=1 lo. Fragment math
// identical to the in-kernel build of rounds 5/6 (operand-swapped D = W*X).
__global__ void build_wtab(const float* __restrict__ wmid,
                           const float* __restrict__ w20,
                           f16* __restrict__ wtab) {
    const int l = blockIdx.x;           // 0..18
    const int lane = threadIdx.x;       // 0..63
    const float* wt = (l < 18) ? wmid + (size_t)l * 576 : w20;
    const int COUT = (l < 18) ? 8 : 1;
    const int n = lane & 15, q = lane >> 4;
#pragma unroll
    for (int g = 0; g < 3; ++g) {
        const int t = g * 4 + q;
        f16x8 hv, lv;
#pragma unroll
        for (int j = 0; j < 8; ++j) {
            float wv = 0.f;
            if (n < 8) {
                if (t <= 8 && n < COUT) wv = wt[(n * 8 + j) * 9 + t];
            } else {
                const int o = n - 8;
                if (t >= 3 && o < COUT) wv = wt[(o * 8 + j) * 9 + (t - 3)];
            }
            const f16 h = (f16)wv;
            hv[j] = h;
            lv[j] = (f16)(wv - (float)h);
        }
        f16* dst = wtab + (size_t)l * WTAB_L + (g * 2) * 512 + lane * 8;
        *(f16x8*)dst = hv;
        *(f16x8*)(dst + 512) = lv;
    }
}

// ---------------- conv1: 1->8 + relu, f32 in -> f16 padded NHWC ---------------
__global__ __launch_bounds__(256) void conv1_kernel(
    const float* __restrict__ in, const float* __restrict__ wt,  // [8][9]
    f16* __restrict__ out)
{
    const int x0 = (blockIdx.x * 64 + threadIdx.x) * 4;
    const int y  = blockIdx.y * 4 + threadIdx.y;
    const int b  = blockIdx.z;
    const float* inb = in + (size_t)b * H * W;

    float patch[3][6];
#pragma unroll
    for (int r = 0; r < 3; ++r) {
        const int iy = y - 1 + r;
        if (iy >= 0 && iy < H) {
            const float* rp = inb + (size_t)iy * W;
            const float4 v = *(const float4*)(rp + x0);
            patch[r][1] = v.x; patch[r][2] = v.y; patch[r][3] = v.z; patch[r][4] = v.w;
            patch[r][0] = (x0 > 0)     ? rp[x0 - 1] : 0.f;
            patch[r][5] = (x0 + 4 < W) ? rp[x0 + 4] : 0.f;
        } else {
#pragma unroll
            for (int k = 0; k < 6; ++k) patch[r][k] = 0.f;
        }
    }

    float acc[8][4];
#pragma unroll
    for (int o = 0; o < 8; ++o) {
        const float* wo = wt + o * 9;
        float a0 = 0.f, a1 = 0.f, a2 = 0.f, a3 = 0.f;
#pragma unroll
        for (int r = 0; r < 3; ++r)
#pragma unroll
            for (int k = 0; k < 3; ++k) {
                const float wv = wo[r * 3 + k];
                a0 = fmaf(wv, patch[r][k + 0], a0);
                a1 = fmaf(wv, patch[r][k + 1], a1);
                a2 = fmaf(wv, patch[r][k + 2], a2);
                a3 = fmaf(wv, patch[r][k + 3], a3);
            }
        acc[o][0] = a0; acc[o][1] = a1; acc[o][2] = a2; acc[o][3] = a3;
    }

#pragma unroll
    for (int j = 0; j < 4; ++j) {
        f16x8 hv;
#pragma unroll
        for (int o = 0; o < 8; ++o)
            hv[o] = (f16)fmaxf(acc[o][j], 0.f);
        const size_t off = (((size_t)b * ROWS + (y + 1)) * COLS + (x0 + j + 8)) * CH;
        *(f16x8*)(out + off) = hv;
    }
}

// ---------------- MFMA conv, pipelined 4-tile strip ---------------------------
// Block 256 = 4 waves; grid (img, 4 x-tiles, 16 y-strips); each block does 4
// y-tiles of (128 px x 8 rows), double-buffered: stage tile t+1 via
// global_load_lds while computing tile t; the pre-barrier vmcnt(0) drain is
// covered by compute. Weights: 6 coalesced 16B loads from precomputed wtab.
// Operand-swapped MFMA (D = W*X): lane(q,n) holds 4 consecutive ch at one px.
template<bool RELU, bool FINAL>
__global__ __launch_bounds__(256) void convmfma(
    const f16* __restrict__ in,            // padded [g,ROWS,COLS,CH] f16
    const f16* __restrict__ wtab_l,        // this layer's fragment table
    f16* __restrict__ outp,                // padded f16 (mid)
    float* __restrict__ out_final)         // unpadded f32 (final)
{
    __shared__ __align__(16) f16 lds[2][10 * RSP * CH];   // 2 x 23200 B

    const int wave = threadIdx.x >> 6, lane = threadIdx.x & 63;
    const int img = blockIdx.x;            // grid.x = img -> XCD affinity
    const int x0 = blockIdx.y * 128;
    const int ybase = blockIdx.z * 32;     // 4 tiles of 8 rows

    // ---- weight fragments: 6 coalesced 16B loads ----
    f16x8 bhi[3], blo[3];
#pragma unroll
    for (int g = 0; g < 3; ++g) {
        const f16* wp = wtab_l + (g * 2) * 512 + lane * 8;
        bhi[g] = *(const f16x8*)wp;
        blo[g] = *(const f16x8*)(wp + 512);
    }

    const char* src = (const char*)in + (size_t)img * PLANE_BYTES + (size_t)x0 * 16;

    // stage rows y0..y0+9 (padded idx), px cols x0..x0+143 into lds[buf]
    auto stage = [&](int buf, int y0) {
        char* dst = (char*)&lds[buf][0];
        for (int qq = wave; qq < 30; qq += 4) {
            const int r = qq / 3, c = qq % 3;
            const char* gs = src + (size_t)(y0 + r) * ROWBYTES;
            char* ld = dst + r * LDS_ROWB;
            if (c < 2) gload_lds16(gs + c * 1024 + lane * 16, ld + c * 1024);
            else       gload_lds4(gs + 2048 + lane * 4, ld + 2048);
        }
    };

    const int n = lane & 15, q = lane >> 4, m = lane & 15;
    int abase[3];
#pragma unroll
    for (int g = 0; g < 3; ++g) {
        const int t = g * 4 + q;
        const int ty = t / 3 - 1, tx = t % 3 - 1;
        abase[g] = (2 * wave + ty + 1) * RSP + (m + tx + 8);
    }
    const int rowoff = q >> 1;             // 0: row Y, 1: row Y+1
    const int choff = (q & 1) * 4;         // ch 0-3 or 4-7

    stage(0, ybase);
    __syncthreads();

    for (int t = 0; t < 4; ++t) {
        if (t < 3) stage((t + 1) & 1, ybase + 8 * (t + 1));

        const f16* L = &lds[t & 1][0];
        const int Y = ybase + 8 * t + 2 * wave;

#pragma unroll
        for (int s = 0; s < 8; ++s) {
            v4f acc = {0.f, 0.f, 0.f, 0.f}, acc2 = {0.f, 0.f, 0.f, 0.f};
#pragma unroll
            for (int g = 0; g < 3; ++g) {
                const f16x8 xv = *(const f16x8*)&L[(abase[g] + 16 * s) * CH];
                acc  = __builtin_amdgcn_mfma_f32_16x16x32_f16(bhi[g], xv, acc,  0, 0, 0);
                acc2 = __builtin_amdgcn_mfma_f32_16x16x32_f16(blo[g], xv, acc2, 0, 0, 0);
            }
            const v4f res = acc + acc2;

            if constexpr (!FINAL) {
                f16x4 hv;
#pragma unroll
                for (int c = 0; c < 4; ++c) {
                    float v = res[c];
                    if (RELU) v = fmaxf(v, 0.f);
                    hv[c] = (f16)v;
                }
                const int gy = Y + rowoff + 1;            // padded row
                const int gx = x0 + 16 * s + n + 8;       // padded col
                *(f16x4*)(outp + ((size_t)img * ROWS + gy) * COLS * CH + (size_t)gx * CH + choff) = hv;
            } else {
                // valid: m=0 (q=0) -> row Y; m=8 (q=2) -> row Y+1
                if ((q & 1) == 0) {
                    const int gy = Y + rowoff, gx = x0 + 16 * s + n;
                    out_final[((size_t)img * H + gy) * W + gx] = res[0];
                }
            }
        }
        if (t < 3) __syncthreads();
    }
}

extern "C" void kernel_launch(void* const* d_in, const int* in_sizes, int n_in,
                              void* d_out, int out_size, void* d_ws, size_t ws_size,
                              hipStream_t stream) {
    const float* x    = (const float*)d_in[0];   // [8,1,512,512]
    const float* w1   = (const float*)d_in[1];   // [8,1,3,3]
    const float* wmid = (const float*)d_in[2];   // [18,8,8,3,3]
    const float* w20  = (const float*)d_in[3];   // [1,8,3,3]
    float* out = (float*)d_out;                  // [8,1,512,512]

    // group size g: 2 plane-sets of g images + wtab must fit in ws
    const size_t wtab_bytes = (size_t)19 * WTAB_L * 2;
    int g = NB;
    while (g > 1 && 2 * (size_t)g * PLANE_BYTES + wtab_bytes > ws_size) g >>= 1;

    f16* act0 = (f16*)d_ws;
    f16* act1 = act0 + (size_t)g * PLANE_ELEMS;
    f16* wtab = act1 + (size_t)g * PLANE_ELEMS;

    zero_borders<<<dim3(37, g, 2), 256, 0, stream>>>(act0, (size_t)g * PLANE_ELEMS);
    build_wtab<<<19, 64, 0, stream>>>(wmid, w20, wtab);

    for (int b0 = 0; b0 < NB; b0 += g) {
        conv1_kernel<<<dim3(2, 128, g), dim3(64, 4), 0, stream>>>(
            x + (size_t)b0 * H * W, w1, act0);
        for (int l = 0; l < 18; ++l) {
            const f16* s0 = (l & 1) ? act1 : act0;
            f16*       d0 = (l & 1) ? act0 : act1;
            convmfma<true, false><<<dim3(g, 4, 16), 256, 0, stream>>>(
                s0, wtab + (size_t)l * WTAB_L, d0, nullptr);
        }
        // 18 mids: last (l=17) wrote act0
        convmfma<false, true><<<dim3(g, 4, 16), 256, 0, stream>>>(
            act0, wtab + (size_t)18 * WTAB_L, nullptr, out + (size_t)b0 * H * W);
    }
}

// Round 8
// 317.287 us; speedup vs baseline: 4.5931x; 1.0811x over previous
//
#include <hip/hip_runtime.h>

typedef _Float16 f16;
typedef _Float16 f16x8 __attribute__((ext_vector_type(8)));
typedef _Float16 f16x4 __attribute__((ext_vector_type(4)));
typedef float v4f __attribute__((ext_vector_type(4)));

constexpr int H = 512, W = 512, NB = 8;
constexpr int ROWS = 514;               // padded rows: y+1 for y in -1..512
constexpr int COLS = 528;               // px p at col p+8, p in -8..519
constexpr int CH = 8;
constexpr size_t ROWBYTES = (size_t)COLS * CH * 2;        // 8448
constexpr size_t PLANE_ELEMS = (size_t)ROWS * COLS * CH;  // f16 per img-plane
constexpr size_t PLANE_BYTES = PLANE_ELEMS * 2;           // 4,342,272

constexpr int RSP = 145;                // LDS row stride in px (+1 pad, r5 fix)
constexpr int RSPC = RSP * CH;          // f16 per LDS row (1160)
constexpr int LDS_ROWB = RSP * 16;      // 2320 B
constexpr int WTAB_L = 3072;            // f16 per layer fragment table

__device__ __forceinline__ void gload_lds16(const void* g, void* l) {
    __builtin_amdgcn_global_load_lds(
        (const __attribute__((address_space(1))) unsigned int*)g,
        (__attribute__((address_space(3))) unsigned int*)l, 16, 0, 0);
}
__device__ __forceinline__ void gload_lds4(const void* g, void* l) {
    __builtin_amdgcn_global_load_lds(
        (const __attribute__((address_space(1))) unsigned int*)g,
        (__attribute__((address_space(3))) unsigned int*)l, 4, 0, 0);
}

// ---------------- zero borders of the 2 plane-sets (act0, act1) ---------------
__global__ void zero_borders(f16* __restrict__ base, size_t set_stride) {
    const int i = blockIdx.x * 256 + threadIdx.x;
    if (i >= 9248) return;
    const int img = blockIdx.y, set = blockIdx.z;
    int row, col;
    if (i < 1056) { row = (i < 528) ? 0 : 513; col = (i < 528) ? i : i - 528; }
    else {
        const int j = i - 1056;
        row = 1 + (j >> 4);
        const int c4 = j & 15;
        col = (c4 < 8) ? c4 : 512 + c4;
    }
    f16x8 z = {};
    f16* p = base + (size_t)set * set_stride + ((size_t)img * ROWS + row) * COLS * CH + (size_t)col * CH;
    *(f16x8*)p = z;
}

// ---------------- precompute per-lane weight fragments (19 layers) ------------
__global__ void build_wtab(const float* __restrict__ wmid,
                           const float* __restrict__ w20,
                           f16* __restrict__ wtab) {
    const int l = blockIdx.x;           // 0..18
    const int lane = threadIdx.x;       // 0..63
    const float* wt = (l < 18) ? wmid + (size_t)l * 576 : w20;
    const int COUT = (l < 18) ? 8 : 1;
    const int n = lane & 15, q = lane >> 4;
#pragma unroll
    for (int g = 0; g < 3; ++g) {
        const int t = g * 4 + q;
        f16x8 hv, lv;
#pragma unroll
        for (int j = 0; j < 8; ++j) {
            float wv = 0.f;
            if (n < 8) {
                if (t <= 8 && n < COUT) wv = wt[(n * 8 + j) * 9 + t];
            } else {
                const int o = n - 8;
                if (t >= 3 && o < COUT) wv = wt[(o * 8 + j) * 9 + (t - 3)];
            }
            const f16 h = (f16)wv;
            hv[j] = h;
            lv[j] = (f16)(wv - (float)h);
        }
        f16* dst = wtab + (size_t)l * WTAB_L + (g * 2) * 512 + lane * 8;
        *(f16x8*)dst = hv;
        *(f16x8*)(dst + 512) = lv;
    }
}

// ---------------- conv1: 1->8 + relu, f32 in -> f16 padded NHWC ---------------
__global__ __launch_bounds__(256) void conv1_kernel(
    const float* __restrict__ in, const float* __restrict__ wt,  // [8][9]
    f16* __restrict__ out)
{
    const int x0 = (blockIdx.x * 64 + threadIdx.x) * 4;
    const int y  = blockIdx.y * 4 + threadIdx.y;
    const int b  = blockIdx.z;
    const float* inb = in + (size_t)b * H * W;

    float patch[3][6];
#pragma unroll
    for (int r = 0; r < 3; ++r) {
        const int iy = y - 1 + r;
        if (iy >= 0 && iy < H) {
            const float* rp = inb + (size_t)iy * W;
            const float4 v = *(const float4*)(rp + x0);
            patch[r][1] = v.x; patch[r][2] = v.y; patch[r][3] = v.z; patch[r][4] = v.w;
            patch[r][0] = (x0 > 0)     ? rp[x0 - 1] : 0.f;
            patch[r][5] = (x0 + 4 < W) ? rp[x0 + 4] : 0.f;
        } else {
#pragma unroll
            for (int k = 0; k < 6; ++k) patch[r][k] = 0.f;
        }
    }

    float acc[8][4];
#pragma unroll
    for (int o = 0; o < 8; ++o) {
        const float* wo = wt + o * 9;
        float a0 = 0.f, a1 = 0.f, a2 = 0.f, a3 = 0.f;
#pragma unroll
        for (int r = 0; r < 3; ++r)
#pragma unroll
            for (int k = 0; k < 3; ++k) {
                const float wv = wo[r * 3 + k];
                a0 = fmaf(wv, patch[r][k + 0], a0);
                a1 = fmaf(wv, patch[r][k + 1], a1);
                a2 = fmaf(wv, patch[r][k + 2], a2);
                a3 = fmaf(wv, patch[r][k + 3], a3);
            }
        acc[o][0] = a0; acc[o][1] = a1; acc[o][2] = a2; acc[o][3] = a3;
    }

#pragma unroll
    for (int j = 0; j < 4; ++j) {
        f16x8 hv;
#pragma unroll
        for (int o = 0; o < 8; ++o)
            hv[o] = (f16)fmaxf(acc[o][j], 0.f);
        const size_t off = (((size_t)b * ROWS + (y + 1)) * COLS + (x0 + j + 8)) * CH;
        *(f16x8*)(out + off) = hv;
    }
}

// ---------------- FUSED 2-layer conv (8->8 relu, 8->8 relu) -------------------
// Block 256 = 4 waves; grid (img, 4 x-tiles, 16 y-chunks of 32 rows).
// Layer A computed into an LDS ring (10 rows x 144 px NHWC f16, same format as
// global planes -> identical ds_read/MFMA pattern and wtab fragments as B).
// Input ring: 12 rows. Per 8-row strip: A-phase (1 row-pair/wave, 9 x-subtiles
// covering B's 1-px halo) -> barrier -> stage next 8 input rows (overlaps B)
// -> B-phase (8 subtiles, global f16x4 stores) -> barrier (drains staging).
// SAME-pad of the intermediate layer: predicated zeroing of A at global edges.
__global__ __launch_bounds__(256) void conv2fused(
    const f16* __restrict__ in,
    const f16* __restrict__ wtA, const f16* __restrict__ wtB,
    f16* __restrict__ outp)
{
    // aring FIRST: input-ring col -1 reads (A halo px, unused output) land in
    // aring's tail -> defined garbage, never before the shared block.
    __shared__ __align__(16) f16 aring[10 * RSPC];    // 23200 B
    __shared__ __align__(16) f16 inring[12 * RSPC];   // 27840 B

    const int wave = threadIdx.x >> 6, lane = threadIdx.x & 63;
    const int img = blockIdx.x, xt = blockIdx.y;
    const int x0 = xt * 128;
    const int base = blockIdx.z * 32;   // B output padded rows [base+1..base+32]

    // weight fragments: 12 coalesced 16B loads
    f16x8 ahiW[3], aloW[3], bhiW[3], bloW[3];
#pragma unroll
    for (int g = 0; g < 3; ++g) {
        const f16* wa = wtA + (g * 2) * 512 + lane * 8;
        ahiW[g] = *(const f16x8*)wa;  aloW[g] = *(const f16x8*)(wa + 512);
        const f16* wb = wtB + (g * 2) * 512 + lane * 8;
        bhiW[g] = *(const f16x8*)wb;  bloW[g] = *(const f16x8*)(wb + 512);
    }

    const char* src = (const char*)in + (size_t)img * PLANE_BYTES + (size_t)x0 * 16;

    // stage rows [r0, r0+cnt) (padded idx, clamped to [0,513]) into slot r%12
    auto stage = [&](int r0, int cnt) {
        for (int qq = wave; qq < cnt * 3; qq += 4) {
            const int rr = qq / 3, c = qq % 3;
            const int row = r0 + rr;
            const int rowc = min(max(row, 0), 513);
            const int slot = ((row % 12) + 12) % 12;
            const char* gs = src + (size_t)rowc * ROWBYTES;
            char* ld = (char*)inring + slot * LDS_ROWB;
            if (c < 2) gload_lds16(gs + c * 1024 + lane * 16, ld + c * 1024);
            else       gload_lds4(gs + 2048 + lane * 4, ld + 2048);
        }
    };

    const int n = lane & 15, q = lane >> 4;
    int tyv[3], txv[3];
#pragma unroll
    for (int g = 0; g < 3; ++g) { const int t = g * 4 + q; tyv[g] = t / 3 - 1; txv[g] = t % 3 - 1; }
    const int rowoff = q >> 1, choff = (q & 1) * 4;
    const bool xe0 = (xt == 0), xe3 = (xt == 3);

    // A-phase: rows (rA, rA+1), px x0-8+16s+n (s=0..8) -> aring
    auto computeA = [&](int rA) {
        int irow[3];
#pragma unroll
        for (int g = 0; g < 3; ++g) irow[g] = ((rA + tyv[g] + 12) % 12) * RSPC;
        const int gyA = rA + rowoff;
        const int wrow = (gyA % 10) * RSPC;
        const bool zr = (gyA == 0) || (gyA == 513);
#pragma unroll
        for (int s = 0; s < 9; ++s) {
            v4f acc = {0.f,0.f,0.f,0.f}, acc2 = {0.f,0.f,0.f,0.f};
#pragma unroll
            for (int g = 0; g < 3; ++g) {
                const f16x8 xv = *(const f16x8*)&inring[irow[g] + (16 * s + n + txv[g]) * CH];
                acc  = __builtin_amdgcn_mfma_f32_16x16x32_f16(ahiW[g], xv, acc,  0, 0, 0);
                acc2 = __builtin_amdgcn_mfma_f32_16x16x32_f16(aloW[g], xv, acc2, 0, 0, 0);
            }
            const v4f res = acc + acc2;
            f16x4 hv;
#pragma unroll
            for (int c = 0; c < 4; ++c) hv[c] = (f16)fmaxf(res[c], 0.f);
            // SAME-pad for layer B: zero A at global borders (rows 0/513,
            // px -1 at xt==0 (col 7, s=0 n=7), px 512 at xt==3 (col 136, s=8 n=8))
            if (zr || (xe0 && s == 0 && n == 7) || (xe3 && s == 8 && n == 8)) {
                hv[0] = (f16)0.f; hv[1] = (f16)0.f; hv[2] = (f16)0.f; hv[3] = (f16)0.f;
            }
            *(f16x4*)&aring[wrow + (16 * s + n) * CH + choff] = hv;
        }
    };

    // B-phase: rows (rB, rB+1), px x0+16s+n (s=0..7) -> global
    auto computeB = [&](int rB) {
        int brow[3];
#pragma unroll
        for (int g = 0; g < 3; ++g) brow[g] = ((rB + tyv[g]) % 10) * RSPC;
        const int gyB = rB + rowoff;
        f16* orow = outp + ((size_t)img * ROWS + gyB) * COLS * CH + (size_t)(x0 + 8) * CH + choff;
#pragma unroll
        for (int s = 0; s < 8; ++s) {
            v4f acc = {0.f,0.f,0.f,0.f}, acc2 = {0.f,0.f,0.f,0.f};
#pragma unroll
            for (int g = 0; g < 3; ++g) {
                const f16x8 xv = *(const f16x8*)&aring[brow[g] + (16 * s + n + txv[g] + 8) * CH];
                acc  = __builtin_amdgcn_mfma_f32_16x16x32_f16(bhiW[g], xv, acc,  0, 0, 0);
                acc2 = __builtin_amdgcn_mfma_f32_16x16x32_f16(bloW[g], xv, acc2, 0, 0, 0);
            }
            const v4f res = acc + acc2;
            f16x4 hv;
#pragma unroll
            for (int c = 0; c < 4; ++c) hv[c] = (f16)fmaxf(res[c], 0.f);
            *(f16x4*)(orow + (size_t)(16 * s + n) * CH) = hv;
        }
    };

    // ---- prime: input rows [base-1..base+10]; A pair (base,base+1) by wave 0
    stage(base - 1, 12);
    __syncthreads();
    if (wave == 0) computeA(base);

    for (int t = 0; t < 4; ++t) {
        computeA(base + 8 * t + 2 + 2 * wave);      // A-new rows [b+8t+2..b+8t+9]
        __syncthreads();                            // A visible; input reads done
        if (t < 3) stage(base + 8 * t + 11, 8);     // overlaps B-phase
        computeB(base + 8 * t + 1 + 2 * wave);      // B rows [b+8t+1..b+8t+8]
        __syncthreads();                            // drains staging + stores
    }
}

// ---------------- final conv (r7 pipelined, FINAL variant) --------------------
template<bool RELU, bool FINAL>
__global__ __launch_bounds__(256) void convmfma(
    const f16* __restrict__ in, const f16* __restrict__ wtab_l,
    f16* __restrict__ outp, float* __restrict__ out_final)
{
    __shared__ __align__(16) f16 lds[2][10 * RSPC];

    const int wave = threadIdx.x >> 6, lane = threadIdx.x & 63;
    const int img = blockIdx.x;
    const int x0 = blockIdx.y * 128;
    const int ybase = blockIdx.z * 32;

    f16x8 bhi[3], blo[3];
#pragma unroll
    for (int g = 0; g < 3; ++g) {
        const f16* wp = wtab_l + (g * 2) * 512 + lane * 8;
        bhi[g] = *(const f16x8*)wp;
        blo[g] = *(const f16x8*)(wp + 512);
    }

    const char* src = (const char*)in + (size_t)img * PLANE_BYTES + (size_t)x0 * 16;
    auto stage = [&](int buf, int y0) {
        char* dst = (char*)&lds[buf][0];
        for (int qq = wave; qq < 30; qq += 4) {
            const int r = qq / 3, c = qq % 3;
            const char* gs = src + (size_t)(y0 + r) * ROWBYTES;
            char* ld = dst + r * LDS_ROWB;
            if (c < 2) gload_lds16(gs + c * 1024 + lane * 16, ld + c * 1024);
            else       gload_lds4(gs + 2048 + lane * 4, ld + 2048);
        }
    };

    const int n = lane & 15, q = lane >> 4, m = lane & 15;
    int abase[3];
#pragma unroll
    for (int g = 0; g < 3; ++g) {
        const int t = g * 4 + q;
        const int ty = t / 3 - 1, tx = t % 3 - 1;
        abase[g] = (2 * wave + ty + 1) * RSP + (m + tx + 8);
    }
    const int rowoff = q >> 1;
    const int choff = (q & 1) * 4;

    stage(0, ybase);
    __syncthreads();

    for (int t = 0; t < 4; ++t) {
        if (t < 3) stage((t + 1) & 1, ybase + 8 * (t + 1));
        const f16* L = &lds[t & 1][0];
        const int Y = ybase + 8 * t + 2 * wave;
#pragma unroll
        for (int s = 0; s < 8; ++s) {
            v4f acc = {0.f,0.f,0.f,0.f}, acc2 = {0.f,0.f,0.f,0.f};
#pragma unroll
            for (int g = 0; g < 3; ++g) {
                const f16x8 xv = *(const f16x8*)&L[(abase[g] + 16 * s) * CH];
                acc  = __builtin_amdgcn_mfma_f32_16x16x32_f16(bhi[g], xv, acc,  0, 0, 0);
                acc2 = __builtin_amdgcn_mfma_f32_16x16x32_f16(blo[g], xv, acc2, 0, 0, 0);
            }
            const v4f res = acc + acc2;
            if constexpr (!FINAL) {
                f16x4 hv;
#pragma unroll
                for (int c = 0; c < 4; ++c) {
                    float v = res[c];
                    if (RELU) v = fmaxf(v, 0.f);
                    hv[c] = (f16)v;
                }
                const int gy = Y + rowoff + 1;
                const int gx = x0 + 16 * s + n + 8;
                *(f16x4*)(outp + ((size_t)img * ROWS + gy) * COLS * CH + (size_t)gx * CH + choff) = hv;
            } else {
                if ((q & 1) == 0) {
                    const int gy = Y + rowoff, gx = x0 + 16 * s + n;
                    out_final[((size_t)img * H + gy) * W + gx] = res[0];
                }
            }
        }
        if (t < 3) __syncthreads();
    }
}

extern "C" void kernel_launch(void* const* d_in, const int* in_sizes, int n_in,
                              void* d_out, int out_size, void* d_ws, size_t ws_size,
                              hipStream_t stream) {
    const float* x    = (const float*)d_in[0];   // [8,1,512,512]
    const float* w1   = (const float*)d_in[1];   // [8,1,3,3]
    const float* wmid = (const float*)d_in[2];   // [18,8,8,3,3]
    const float* w20  = (const float*)d_in[3];   // [1,8,3,3]
    float* out = (float*)d_out;                  // [8,1,512,512]

    const size_t wtab_bytes = (size_t)19 * WTAB_L * 2;
    int g = NB;
    while (g > 1 && 2 * (size_t)g * PLANE_BYTES + wtab_bytes > ws_size) g >>= 1;

    f16* act0 = (f16*)d_ws;
    f16* act1 = act0 + (size_t)g * PLANE_ELEMS;
    f16* wtab = act1 + (size_t)g * PLANE_ELEMS;

    zero_borders<<<dim3(37, g, 2), 256, 0, stream>>>(act0, (size_t)g * PLANE_ELEMS);
    build_wtab<<<19, 64, 0, stream>>>(wmid, w20, wtab);

    for (int b0 = 0; b0 < NB; b0 += g) {
        conv1_kernel<<<dim3(2, 128, g), dim3(64, 4), 0, stream>>>(
            x + (size_t)b0 * H * W, w1, act0);
        // 9 fused pairs: layers (0,1),(2,3),...,(16,17); ping-pong act0<->act1
        for (int k = 0; k < 9; ++k) {
            const f16* s0 = (k & 1) ? act1 : act0;
            f16*       d0 = (k & 1) ? act0 : act1;
            conv2fused<<<dim3(g, 4, 16), 256, 0, stream>>>(
                s0, wtab + (size_t)(2 * k) * WTAB_L, wtab + (size_t)(2 * k + 1) * WTAB_L, d0);
        }
        // after 9 pairs: result in act1
        convmfma<false, true><<<dim3(g, 4, 16), 256, 0, stream>>>(
            act1, wtab + (size_t)18 * WTAB_L, nullptr, out + (size_t)b0 * H * W);
    }
}